// Round 5
// baseline (365.500 us; speedup 1.0000x reference)
//
#include <hip/hip_runtime.h>
#include <hip/hip_bf16.h>

// LPKT forward. B=128, S=128, C=128, D=64.
//  - P1/P2: parallel precompute off the sequential critical path.
//  - K3: one 512-thread workgroup per batch element, 127-step recurrence.
//    h in registers (8 waves x 32c x 32d), bf16 shadow in LDS for MFMA.
//    3 barriers/step. Serial waves (w4/w5) do MFMA in phA so phB is pure
//    LG-chain; q rows as f32 ring; pre-streams in 32-slot ring; refills at
//    16-step block boundaries (branchless inner loop).

#define NB 128
#define NS 128
#define NC 128
#define ND 64
#define POS (NB*NS)

typedef __attribute__((ext_vector_type(8))) short short8;
typedef __attribute__((ext_vector_type(4))) float f32x4;

__device__ __forceinline__ float sigm(float x){ return 1.f/(1.f+__expf(-x)); }
__device__ __forceinline__ float rl(float v,int j){
  return __int_as_float(__builtin_amdgcn_readlane(__float_as_int(v), j));
}

#define HBF(c, d) ((((c)<<6) + (d)) ^ (((c)&7)<<3))

#define DPP_ADD(v, CTRL) ((v) + __int_as_float(__builtin_amdgcn_update_dpp(0, __float_as_int(v), CTRL, 0xF, 0xF, true)))
#define DPP_ROWSUM(v) do { v = DPP_ADD(v,0x111); v = DPP_ADD(v,0x112); v = DPP_ADD(v,0x114); v = DPP_ADD(v,0x118); } while(0)

// init + sum_{j<32} (lane koff+j of src) * wcol[j]
__device__ __forceinline__ float rlmv32(float src, const float* wcol, int koff, float init){
  float a0=init,a1=0.f,a2=0.f,a3=0.f;
  #pragma unroll
  for (int j=0;j<32;j+=4){
    a0=fmaf(rl(src,koff+j+0),wcol[j+0],a0);
    a1=fmaf(rl(src,koff+j+1),wcol[j+1],a1);
    a2=fmaf(rl(src,koff+j+2),wcol[j+2],a2);
    a3=fmaf(rl(src,koff+j+3),wcol[j+3],a3);
  }
  return (a0+a1)+(a2+a3);
}

// ---------------- P1: AL = [e,at,c]@W1+b1 ; pre4 = it@W4c+b4 ; pre5 = e@W5a+b5
__global__ __launch_bounds__(64) void lpkt_pre1(
    const int* __restrict__ qseq, const int* __restrict__ cseq,
    const int* __restrict__ itseq, const int* __restrict__ atseq,
    const float* __restrict__ E_q, const float* __restrict__ E_c,
    const float* __restrict__ E_it, const float* __restrict__ E_at,
    const float* __restrict__ W1, const float* __restrict__ b1,
    const float* __restrict__ W4, const float* __restrict__ b4,
    const float* __restrict__ W5, const float* __restrict__ b5,
    float* __restrict__ AL, float* __restrict__ pre4, float* __restrict__ pre5)
{
  __shared__ float sx[4][192];
  __shared__ float sit[4][64];
  const int d = threadIdx.x;
  #pragma unroll
  for (int i = 0; i < 4; ++i) {
    int p = blockIdx.x + i*4096;
    sx[i][d]      = E_q[qseq[p]*ND + d];
    sx[i][64+d]   = E_at[atseq[p]*ND + d];
    sx[i][128+d]  = E_c[cseq[p]*ND + d];
    sit[i][d]     = E_it[itseq[p]*ND + d];
  }
  __syncthreads();
  float al[4], p4[4], p5[4];
  const float b1d = b1[d], b4d = b4[d], b5d = b5[d];
  #pragma unroll
  for (int i = 0; i < 4; ++i) { al[i] = b1d; p4[i] = b4d; p5[i] = b5d; }
  for (int k = 0; k < 192; ++k) {
    float wv = W1[k*ND + d];
    #pragma unroll
    for (int i = 0; i < 4; ++i) al[i] = fmaf(sx[i][k], wv, al[i]);
  }
  for (int k = 0; k < 64; ++k) {
    float wv4 = W4[(128+k)*ND + d];
    float wv5 = W5[k*ND + d];
    #pragma unroll
    for (int i = 0; i < 4; ++i) {
      p4[i] = fmaf(sit[i][k], wv4, p4[i]);
      p5[i] = fmaf(sx[i][k],  wv5, p5[i]);
    }
  }
  #pragma unroll
  for (int i = 0; i < 4; ++i) {
    int p = blockIdx.x + i*4096;
    AL[p*ND + d]   = al[i];
    pre4[p*ND + d] = p4[i];
    pre5[p*ND + d] = p5[i];
  }
}

// ---------------- P2: pre2/pre3 = [AL(t-1)|0, it, AL(t)] @ W{2,3}[0:192] + b
__global__ __launch_bounds__(64) void lpkt_pre2(
    const int* __restrict__ itseq, const float* __restrict__ E_it,
    const float* __restrict__ AL,
    const float* __restrict__ W2, const float* __restrict__ b2,
    const float* __restrict__ W3, const float* __restrict__ b3,
    float* __restrict__ pre2, float* __restrict__ pre3)
{
  __shared__ float sx[4][192];
  const int d = threadIdx.x;
  int bs4[4];
  #pragma unroll
  for (int i = 0; i < 4; ++i) {
    int p = blockIdx.x + i*4064;
    int b = p / 127;
    int t = p - b*127;
    int bs = b*NS + t;
    bs4[i] = bs;
    sx[i][d]     = (t > 0) ? AL[(bs-1)*ND + d] : 0.f;
    sx[i][64+d]  = E_it[itseq[bs]*ND + d];
    sx[i][128+d] = AL[bs*ND + d];
  }
  __syncthreads();
  float a2[4], a3[4];
  const float b2d = b2[d], b3d = b3[d];
  #pragma unroll
  for (int i = 0; i < 4; ++i) { a2[i] = b2d; a3[i] = b3d; }
  for (int k = 0; k < 192; ++k) {
    float w2v = W2[k*ND + d];
    float w3v = W3[k*ND + d];
    #pragma unroll
    for (int i = 0; i < 4; ++i) {
      a2[i] = fmaf(sx[i][k], w2v, a2[i]);
      a3[i] = fmaf(sx[i][k], w3v, a3[i]);
    }
  }
  #pragma unroll
  for (int i = 0; i < 4; ++i) {
    pre2[bs4[i]*ND + d] = a2[i];
    pre3[bs4[i]*ND + d] = a3[i];
  }
}

// MFMA: wave computes its (c32 x d32) quadrant of P^T from sh_hbf + aW
#define MFMA_COMPUTE() do {                                                  \
  _Pragma("unroll")                                                          \
  for (int t2=0;t2<2;++t2){                                                  \
    _Pragma("unroll")                                                        \
    for (int k0=0;k0<2;++k0){                                                \
      short8 bf = *(const short8*)&sh_hbf[HBF(32*Wq+16*t2+li, 32*k0+8*g)];   \
      acc[0][t2] = __builtin_amdgcn_mfma_f32_16x16x32_bf16(aW[0][k0], bf, acc[0][t2], 0,0,0); \
      acc[1][t2] = __builtin_amdgcn_mfma_f32_16x16x32_bf16(aW[1][k0], bf, acc[1][t2], 0,0,0); \
    }                                                                        \
  }                                                                          \
} while(0)

// ---------------- K3: sequential recurrence
__global__ __launch_bounds__(512,1) void lpkt_seq(
    const int* __restrict__ qseq, const float* __restrict__ qmat,
    const float* __restrict__ h0,
    const float* __restrict__ W2, const float* __restrict__ W3,
    const float* __restrict__ W4, const float* __restrict__ W5,
    const float* __restrict__ pre2, const float* __restrict__ pre3,
    const float* __restrict__ pre4, const float* __restrict__ pre5,
    float* __restrict__ out)
{
  __shared__ __align__(16) unsigned short sh_hbf[NC*ND];  // 16KB bf16 shadow
  __shared__ float sh_pre[4][32][64];                     // 32KB pre-stream ring
  __shared__ float sh_qf[32][NC];                         // 16KB q-row f32 ring
  __shared__ float sh_htp[4][64];
  __shared__ float sh_pa[4][64];
  __shared__ float sh_py[64];
  __shared__ float sh_LG[64];
  __shared__ float sh_lgp[2][64];
  __shared__ float sh_out[NS];

  const int tid = threadIdx.x;
  const int w = tid>>6, l = tid&63;
  const int g = l>>4, li = l&15;
  const int b = blockIdx.x;
  const int Wq = w & 3;
  const int mm = (w>>2)*2;

  if (w==4 || w==5) __builtin_amdgcn_s_setprio(1);  // critical serial waves

  // ---- static weights in registers
  short8 aW[2][2];
  #pragma unroll
  for (int mloc=0;mloc<2;++mloc){
    #pragma unroll
    for (int k0=0;k0<2;++k0){
      short8 v;
      #pragma unroll
      for (int j=0;j<8;++j){
        __hip_bfloat16 hb = __float2bfloat16(W4[(32*k0+8*g+j)*ND + 16*(mm+mloc)+li]);
        v[j] = *(short*)&hb;
      }
      aW[mloc][k0] = v;
    }
  }
  float wsA[32];
  {
    const float* srcA = nullptr;
    if      (w==0) srcA = W2 + 192*ND;
    else if (w==1) srcA = W2 + 224*ND;
    else if (w==2) srcA = W3 + 192*ND;
    else if (w==6) srcA = W3 + 224*ND;
    else if (w==3) srcA = W5 + 64*ND;
    else if (w==7) srcA = W5 + 96*ND;
    if (srcA){
      #pragma unroll
      for (int j=0;j<32;++j) wsA[j] = srcA[j*ND + l];
    }
  }
  float wsB[32];
  if (w==4 || w==5){
    const float* srcB = W4 + (w==4 ? 64 : 96)*ND;
    #pragma unroll
    for (int j=0;j<32;++j) wsB[j] = srcB[j*ND + l];
  }

  // ---- init h in registers + bf16 shadow
  float hreg[2][2][4];
  #pragma unroll
  for (int mloc=0;mloc<2;++mloc){
    #pragma unroll
    for (int t2=0;t2<2;++t2){
      int c  = 32*Wq + 16*t2 + li;
      int d0 = 16*(mm+mloc) + 4*g;
      float4 v = *(const float4*)&h0[c*ND + d0];
      hreg[mloc][t2][0]=v.x; hreg[mloc][t2][1]=v.y;
      hreg[mloc][t2][2]=v.z; hreg[mloc][t2][3]=v.w;
      __hip_bfloat162 c01 = __float22bfloat162_rn(make_float2(v.x,v.y));
      __hip_bfloat162 c23 = __float22bfloat162_rn(make_float2(v.z,v.w));
      uint2 pk; pk.x = *(unsigned*)&c01; pk.y = *(unsigned*)&c23;
      *(uint2*)&sh_hbf[HBF(c,d0)] = pk;
    }
  }

  // ---- qf ring init: rows 0..16
  #pragma unroll
  for (int rep=0; rep<5; ++rep){
    int idx = rep*512 + tid;
    if (idx < 17*NC){
      int i = idx >> 7, col = idx & 127;
      int qrow = qseq[b*NS + i];
      sh_qf[i][col] = qmat[qrow*NC + col];
    }
  }
  // ---- pre ring init: steps 0..31
  #pragma unroll
  for (int k2=0;k2<4;++k2){
    int f4id = tid*4 + k2;
    int r = f4id >> 4;
    int col = (f4id & 15)*4;
    int s = r >> 5, off = r & 31;
    const float* ps = (s==0)?pre2:(s==1)?pre3:(s==2)?pre4:pre5;
    float4 v = *(const float4*)&ps[(b*NS + off)*ND + col];
    *(float4*)&sh_pre[s][off][col] = v;
  }
  if (tid==0) sh_out[0] = 0.f;
  __syncthreads();

  // ---- bootstrap htp: q(0) . h_init
  {
    float part[2][4] = {{0.f,0.f,0.f,0.f},{0.f,0.f,0.f,0.f}};
    #pragma unroll
    for (int t2=0;t2<2;++t2){
      float qv = sh_qf[0][32*Wq+16*t2+li];
      #pragma unroll
      for (int mloc=0;mloc<2;++mloc)
        #pragma unroll
        for (int r=0;r<4;++r)
          part[mloc][r] = fmaf(qv, hreg[mloc][t2][r], part[mloc][r]);
    }
    #pragma unroll
    for (int mloc=0;mloc<2;++mloc)
      #pragma unroll
      for (int r=0;r<4;++r){ float v=part[mloc][r]; DPP_ROWSUM(v); part[mloc][r]=v; }
    if (li==15){
      #pragma unroll
      for (int mloc=0;mloc<2;++mloc){
        float4 pv; pv.x=part[mloc][0]; pv.y=part[mloc][1]; pv.z=part[mloc][2]; pv.w=part[mloc][3];
        *(float4*)&sh_htp[Wq][16*(mm+mloc)+4*g] = pv;
      }
    }
  }
  __syncthreads();

  int t = 0;
  for (int blk=0; blk<8; ++blk){
    // ---- block-boundary refills (visible >=2 barriers before first read)
    if (blk >= 1){
      if (blk <= 6){
        #pragma unroll
        for (int j=0;j<2;++j){
          int f4 = tid*2 + j;
          int s = f4 >> 8;
          int rem = f4 & 255;
          int i = rem >> 4;
          int col = (rem & 15)*4;
          int ts = 16*blk + 16 + i;
          const float* ps = (s==0)?pre2:(s==1)?pre3:(s==2)?pre4:pre5;
          float4 v = *(const float4*)&ps[(b*NS + ts)*ND + col];
          *(float4*)&sh_pre[s][ts & 31][col] = v;
        }
      }
      #pragma unroll
      for (int rep=0; rep<4; ++rep){
        int idx = rep*512 + tid;
        int i = idx >> 7, col = idx & 127;
        int rr = 16*blk + 1 + i;
        if (rr < 128){
          int qrow = qseq[b*NS + rr];
          sh_qf[rr & 31][col] = qmat[qrow*NC + col];
        }
      }
    }
    const int nst = (blk<7) ? 16 : 15;
    for (int it=0; it<nst; ++it, ++t){
      const int slot = t & 31;
      f32x4 acc[2][2];
      #pragma unroll
      for (int mloc=0;mloc<2;++mloc)
        #pragma unroll
        for (int t2=0;t2<2;++t2)
          acc[mloc][t2] = (f32x4){0.f,0.f,0.f,0.f};
      float pv2=0.f, pv3=0.f, pv4=0.f, pv5=0.f;

      // ---- phA: dots (w0,1,2,6,3) | MFMA + stream prefetch (w4,5,7)
      if (w==4 || w==5 || w==7){
        if (w==4){ pv2=sh_pre[0][slot][l]; pv3=sh_pre[1][slot][l]; pv4=sh_pre[2][slot][l]; }
        else if (w==5){ pv2=sh_pre[0][slot][l]; pv3=sh_pre[1][slot][l]; }
        else { pv5=sh_pre[3][slot][l]; }
        MFMA_COMPUTE();
      } else {
        float ht = (sh_htp[0][l]+sh_htp[1][l])+(sh_htp[2][l]+sh_htp[3][l]);
        if      (w==0) sh_pa[0][l] = rlmv32(ht, wsA, 0,  0.f);
        else if (w==1) sh_pa[1][l] = rlmv32(ht, wsA, 32, 0.f);
        else if (w==2) sh_pa[2][l] = rlmv32(ht, wsA, 0,  0.f);
        else if (w==6) sh_pa[3][l] = rlmv32(ht, wsA, 32, 0.f);
        else           sh_py[l]    = rlmv32(ht, wsA, 0,  0.f);   // w3: y-lo
      }
      __syncthreads();

      // ---- phB: serial LG chain (w4,w5) | y finish (w7) | MFMA (others)
      if (w==4){
        float a2v = sh_pa[0][l] + sh_pa[1][l] + pv2;
        float a3v = sh_pa[2][l] + sh_pa[3][l] + pv3;
        float LGl = sigm(a3v) * sigm(2.f*a2v);   // == sigm(a3)*(tanh(a2)+1)/2
        sh_LG[l] = LGl;
        sh_lgp[0][l] = rlmv32(LGl, wsB, 0, pv4);
      } else if (w==5){
        float a2v = sh_pa[0][l] + sh_pa[1][l] + pv2;
        float a3v = sh_pa[2][l] + sh_pa[3][l] + pv3;
        float LGl = sigm(a3v) * sigm(2.f*a2v);
        sh_lgp[1][l] = rlmv32(LGl, wsB, 32, 0.f);
      } else if (w==7){
        if (t > 0){
          float ht = (sh_htp[0][l]+sh_htp[1][l])+(sh_htp[2][l]+sh_htp[3][l]);
          float z = rlmv32(ht, wsA, 32, pv5 + sh_py[l]);
          float yv = sigm(z);
          DPP_ROWSUM(yv);
          float s = (rl(yv,15)+rl(yv,31))+(rl(yv,47)+rl(yv,63));
          if (l==0) sh_out[t] = s*(1.f/64.f);
        }
      } else {
        MFMA_COMPUTE();
      }
      __syncthreads();

      // ---- phC: elementwise update + bf16 shadow + DPP ht partials
      {
        const int sn = (t+1) & 31;
        float4 LG4[2], GI[2];
        #pragma unroll
        for (int mloc=0;mloc<2;++mloc){
          int d0 = 16*(mm+mloc)+4*g;
          LG4[mloc] = *(const float4*)&sh_LG[d0];
          float4 g0v = *(const float4*)&sh_lgp[0][d0];
          float4 g1v = *(const float4*)&sh_lgp[1][d0];
          float4 gi; gi.x=g0v.x+g1v.x; gi.y=g0v.y+g1v.y; gi.z=g0v.z+g1v.z; gi.w=g0v.w+g1v.w;
          GI[mloc] = gi;
        }
        float qc[2], qn[2];
        #pragma unroll
        for (int t2=0;t2<2;++t2){
          int c = 32*Wq + 16*t2 + li;
          qc[t2] = sh_qf[slot][c];
          qn[t2] = sh_qf[sn][c];
        }
        float part[2][4] = {{0.f,0.f,0.f,0.f},{0.f,0.f,0.f,0.f}};
        #pragma unroll
        for (int t2=0;t2<2;++t2){
          int c = 32*Wq + 16*t2 + li;
          #pragma unroll
          for (int mloc=0;mloc<2;++mloc){
            float hn0 = fmaf(qc[t2], LG4[mloc].x, sigm(acc[mloc][t2][0]+GI[mloc].x)*hreg[mloc][t2][0]);
            float hn1 = fmaf(qc[t2], LG4[mloc].y, sigm(acc[mloc][t2][1]+GI[mloc].y)*hreg[mloc][t2][1]);
            float hn2 = fmaf(qc[t2], LG4[mloc].z, sigm(acc[mloc][t2][2]+GI[mloc].z)*hreg[mloc][t2][2]);
            float hn3 = fmaf(qc[t2], LG4[mloc].w, sigm(acc[mloc][t2][3]+GI[mloc].w)*hreg[mloc][t2][3]);
            hreg[mloc][t2][0]=hn0; hreg[mloc][t2][1]=hn1;
            hreg[mloc][t2][2]=hn2; hreg[mloc][t2][3]=hn3;
            part[mloc][0] = fmaf(qn[t2], hn0, part[mloc][0]);
            part[mloc][1] = fmaf(qn[t2], hn1, part[mloc][1]);
            part[mloc][2] = fmaf(qn[t2], hn2, part[mloc][2]);
            part[mloc][3] = fmaf(qn[t2], hn3, part[mloc][3]);
            __hip_bfloat162 c01 = __float22bfloat162_rn(make_float2(hn0,hn1));
            __hip_bfloat162 c23 = __float22bfloat162_rn(make_float2(hn2,hn3));
            uint2 pk; pk.x=*(unsigned*)&c01; pk.y=*(unsigned*)&c23;
            *(uint2*)&sh_hbf[HBF(c, 16*(mm+mloc)+4*g)] = pk;
          }
        }
        #pragma unroll
        for (int mloc=0;mloc<2;++mloc)
          #pragma unroll
          for (int r=0;r<4;++r){ float v=part[mloc][r]; DPP_ROWSUM(v); part[mloc][r]=v; }
        if (li==15){
          #pragma unroll
          for (int mloc=0;mloc<2;++mloc){
            float4 pv; pv.x=part[mloc][0]; pv.y=part[mloc][1]; pv.z=part[mloc][2]; pv.w=part[mloc][3];
            *(float4*)&sh_htp[Wq][16*(mm+mloc)+4*g] = pv;
          }
        }
      }
      __syncthreads();
    }
  }

  // ---- final output position 127
  if (w==3){
    float ht = (sh_htp[0][l]+sh_htp[1][l])+(sh_htp[2][l]+sh_htp[3][l]);
    sh_py[l] = rlmv32(ht, wsA, 0, 0.f);
  }
  __syncthreads();
  if (w==7){
    float ht = (sh_htp[0][l]+sh_htp[1][l])+(sh_htp[2][l]+sh_htp[3][l]);
    float z = rlmv32(ht, wsA, 32, sh_pre[3][31][l] + sh_py[l]);
    float yv = sigm(z);
    DPP_ROWSUM(yv);
    float s = (rl(yv,15)+rl(yv,31))+(rl(yv,47)+rl(yv,63));
    if (l==0) sh_out[127] = s*(1.f/64.f);
  }
  __syncthreads();
  if (tid < NS) out[b*NS + tid] = sh_out[tid];
}

extern "C" void kernel_launch(void* const* d_in, const int* in_sizes, int n_in,
                              void* d_out, int out_size, void* d_ws, size_t ws_size,
                              hipStream_t stream)
{
  const int*   qseq  = (const int*)d_in[0];
  const int*   cseq  = (const int*)d_in[1];
  const int*   itseq = (const int*)d_in[2];
  const int*   atseq = (const int*)d_in[3];
  const float* E_q   = (const float*)d_in[4];
  const float* E_c   = (const float*)d_in[5];
  const float* E_it  = (const float*)d_in[6];
  const float* E_at  = (const float*)d_in[7];
  const float* qmat  = (const float*)d_in[8];
  const float* h0    = (const float*)d_in[9];
  const float* W1    = (const float*)d_in[10];
  const float* b1    = (const float*)d_in[11];
  const float* W2    = (const float*)d_in[12];
  const float* b2    = (const float*)d_in[13];
  const float* W3    = (const float*)d_in[14];
  const float* b3    = (const float*)d_in[15];
  const float* W4    = (const float*)d_in[16];
  const float* b4    = (const float*)d_in[17];
  const float* W5    = (const float*)d_in[18];
  const float* b5    = (const float*)d_in[19];
  float* out = (float*)d_out;

  float* wsf  = (float*)d_ws;
  float* AL   = wsf;
  float* pre2 = wsf + 1*POS*ND;
  float* pre3 = wsf + 2*POS*ND;
  float* pre4 = wsf + 3*POS*ND;
  float* pre5 = wsf + 4*POS*ND;

  lpkt_pre1<<<4096, 64, 0, stream>>>(qseq, cseq, itseq, atseq,
                                     E_q, E_c, E_it, E_at,
                                     W1, b1, W4, b4, W5, b5,
                                     AL, pre4, pre5);
  lpkt_pre2<<<4064, 64, 0, stream>>>(itseq, E_it, AL, W2, b2, W3, b3, pre2, pre3);
  lpkt_seq<<<128, 512, 0, stream>>>(qseq, qmat, h0, W2, W3, W4, W5,
                                    pre2, pre3, pre4, pre5, out);
}

// Round 6
// 336.619 us; speedup vs baseline: 1.0858x; 1.0858x over previous
//
#include <hip/hip_runtime.h>
#include <hip/hip_bf16.h>

// LPKT forward. B=128, S=128, C=128, D=64.
//  - lpkt_pre: fused precompute (AL -> pre2/3, pre4, pre5), 16 positions/block,
//    outputs pre-scaled by -log2e (and -2log2e for pre2) for exp2-based sigmoids.
//  - lpkt_seq: one 512-thread block per batch, 127-step recurrence with TWO
//    barriers per step. h in registers (8 waves x 32c x 32d), bf16 shadow in
//    LDS for MFMA (P' = h @ (-log2e*W4a)). Serial chain (a2,a3,LG,lgit) done
//    redundantly+fused in w4/w5 (no cross-wave exchange); y in w6; ring
//    refills isolated to w3 (q rows) / w7 (pre streams).

#define NB 128
#define NS 128
#define NC 128
#define ND 64
#define POS (NB*NS)

typedef __attribute__((ext_vector_type(8))) short short8;
typedef __attribute__((ext_vector_type(4))) float f32x4;

__device__ __forceinline__ float rl(float v,int j){
  return __int_as_float(__builtin_amdgcn_readlane(__float_as_int(v), j));
}
#define HBF(c, d) ((((c)<<6) + (d)) ^ (((c)&7)<<3))
#define DPP_ADD(v, CTRL) ((v) + __int_as_float(__builtin_amdgcn_update_dpp(0, __float_as_int(v), CTRL, 0xF, 0xF, true)))
#define DPP_ROWSUM(v) do { v = DPP_ADD(v,0x111); v = DPP_ADD(v,0x112); v = DPP_ADD(v,0x114); v = DPP_ADD(v,0x118); } while(0)

#define SC1 (-1.4426950408889634f)   /* -log2(e) */

__device__ __forceinline__ float gsig(float zp){   // sigmoid given pre-scaled arg
  return __builtin_amdgcn_rcpf(1.f + __builtin_amdgcn_exp2f(zp));
}

// ---------------- fused precompute: 16 positions per 64-thread block
__global__ __launch_bounds__(64) void lpkt_pre(
    const int* __restrict__ qseq, const int* __restrict__ cseq,
    const int* __restrict__ itseq, const int* __restrict__ atseq,
    const float* __restrict__ E_q, const float* __restrict__ E_c,
    const float* __restrict__ E_it, const float* __restrict__ E_at,
    const float* __restrict__ W1, const float* __restrict__ b1,
    const float* __restrict__ W2, const float* __restrict__ b2,
    const float* __restrict__ W3, const float* __restrict__ b3,
    const float* __restrict__ W4, const float* __restrict__ b4,
    const float* __restrict__ W5, const float* __restrict__ b5,
    float* __restrict__ pre2, float* __restrict__ pre3,
    float* __restrict__ pre4, float* __restrict__ pre5)
{
  __shared__ float sx[17][192];   // [e|at|c] for positions t0-1 .. t0+15
  __shared__ float sit[16][64];
  __shared__ float sal[17][64];
  const int d = threadIdx.x;
  const int bb = blockIdx.x >> 3;
  const int t0 = (blockIdx.x & 7) * 16;

  #pragma unroll 4
  for (int i = 0; i < 17; ++i){
    int tt = t0 - 1 + i;
    if (tt >= 0){
      int p = bb*NS + tt;
      sx[i][d]      = E_q[qseq[p]*ND + d];
      sx[i][64+d]   = E_at[atseq[p]*ND + d];
      sx[i][128+d]  = E_c[cseq[p]*ND + d];
    } else {
      sx[i][d] = 0.f; sx[i][64+d] = 0.f; sx[i][128+d] = 0.f;
    }
  }
  #pragma unroll 4
  for (int i = 0; i < 16; ++i){
    int p = bb*NS + t0 + i;
    sit[i][d] = E_it[itseq[p]*ND + d];
  }
  __syncthreads();

  // AL for 17 positions
  {
    float al[17];
    float b1d = b1[d];
    #pragma unroll
    for (int i=0;i<17;++i) al[i] = b1d;
    for (int k=0;k<192;++k){
      float wv = W1[k*ND + d];
      #pragma unroll
      for (int i=0;i<17;++i) al[i] = fmaf(sx[i][k], wv, al[i]);
    }
    if (t0 == 0) al[0] = 0.f;         // learning_pre at t=0 is zeros
    #pragma unroll
    for (int i=0;i<17;++i) sal[i][d] = al[i];
  }
  __syncthreads();

  // pre2/pre3
  float a2[16], a3[16];
  {
    float b2d = b2[d], b3d = b3[d];
    #pragma unroll
    for (int i=0;i<16;++i){ a2[i]=b2d; a3[i]=b3d; }
    for (int k=0;k<64;++k){
      float w2v = W2[k*ND+d], w3v = W3[k*ND+d];
      #pragma unroll
      for (int i=0;i<16;++i){ a2[i]=fmaf(sal[i][k],w2v,a2[i]); a3[i]=fmaf(sal[i][k],w3v,a3[i]); }
    }
    for (int k=0;k<64;++k){
      float w2v = W2[(64+k)*ND+d], w3v = W3[(64+k)*ND+d];
      #pragma unroll
      for (int i=0;i<16;++i){ a2[i]=fmaf(sit[i][k],w2v,a2[i]); a3[i]=fmaf(sit[i][k],w3v,a3[i]); }
    }
    for (int k=0;k<64;++k){
      float w2v = W2[(128+k)*ND+d], w3v = W3[(128+k)*ND+d];
      #pragma unroll
      for (int i=0;i<16;++i){ a2[i]=fmaf(sal[i+1][k],w2v,a2[i]); a3[i]=fmaf(sal[i+1][k],w3v,a3[i]); }
    }
  }
  // pre4/pre5
  float p4[16], p5[16];
  {
    float b4d = b4[d], b5d = b5[d];
    #pragma unroll
    for (int i=0;i<16;++i){ p4[i]=b4d; p5[i]=b5d; }
    for (int k=0;k<64;++k){
      float w4v = W4[(128+k)*ND+d], w5v = W5[k*ND+d];
      #pragma unroll
      for (int i=0;i<16;++i){ p4[i]=fmaf(sit[i][k],w4v,p4[i]); p5[i]=fmaf(sx[i+1][k],w5v,p5[i]); }
    }
  }
  #pragma unroll
  for (int i=0;i<16;++i){
    int p = (bb*NS + t0 + i)*ND + d;
    pre2[p] = a2[i]*(2.f*SC1);
    pre3[p] = a3[i]*SC1;
    pre4[p] = p4[i]*SC1;
    pre5[p] = p5[i]*SC1;
  }
}

// ---------------- sequential recurrence
__global__ __launch_bounds__(512,1) void lpkt_seq(
    const int* __restrict__ qseq, const float* __restrict__ qmat,
    const float* __restrict__ h0,
    const float* __restrict__ W2, const float* __restrict__ W3,
    const float* __restrict__ W4, const float* __restrict__ W5,
    const float* __restrict__ pre2, const float* __restrict__ pre3,
    const float* __restrict__ pre4, const float* __restrict__ pre5,
    float* __restrict__ out)
{
  __shared__ __align__(16) unsigned short sh_hbf[NC*ND];  // 16KB bf16 shadow
  __shared__ float sh_pre[32][4][64];                     // 32KB stream ring [slot][stream][d]
  __shared__ float sh_qf[32][NC];                         // 16KB q-row ring
  __shared__ float sh_htp[4][64];
  __shared__ float sh_LG[64];
  __shared__ float sh_lgp[2][64];
  __shared__ float sh_out[NS];

  const int tid = threadIdx.x;
  const int w = tid>>6, l = tid&63;
  const int g = l>>4, li = l&15;
  const int b = blockIdx.x;
  const int Wq = w & 3, mm = (w>>2)*2;

  if (w==4 || w==5) __builtin_amdgcn_s_setprio(1);

  // MFMA A-frags: W4a columns scaled by -log2e
  short8 aW[2][2];
  #pragma unroll
  for (int mloc=0;mloc<2;++mloc)
    #pragma unroll
    for (int k0=0;k0<2;++k0){
      short8 v;
      #pragma unroll
      for (int j=0;j<8;++j){
        __hip_bfloat16 hb = __float2bfloat16(W4[(32*k0+8*g+j)*ND + 16*(mm+mloc)+li] * SC1);
        v[j] = *(short*)&hb;
      }
      aW[mloc][k0] = v;
    }

  // chain weights (register-resident)
  float ws2[64], ws3[64], wsB[32];
  if (w==4 || w==5){
    #pragma unroll
    for (int j=0;j<64;++j) ws2[j] = W2[(192+j)*ND + l] * (2.f*SC1);
    #pragma unroll
    for (int j=0;j<64;++j) ws3[j] = W3[(192+j)*ND + l] * SC1;
    const float* pb = W4 + ((w==4)?64:96)*ND;
    #pragma unroll
    for (int j=0;j<32;++j) wsB[j] = pb[j*ND + l] * SC1;
  } else if (w==6){
    #pragma unroll
    for (int j=0;j<64;++j) ws2[j] = W5[(64+j)*ND + l] * SC1;
  }

  // h init in regs + bf16 shadow
  float hreg[2][2][4];
  int wofs[2][2], bfofs[2][2];
  #pragma unroll
  for (int mloc=0;mloc<2;++mloc)
    #pragma unroll
    for (int t2=0;t2<2;++t2){
      int c  = 32*Wq + 16*t2 + li;
      int d0 = 16*(mm+mloc) + 4*g;
      wofs[t2][mloc] = HBF(c, d0);
      float4 v = *(const float4*)&h0[c*ND + d0];
      hreg[mloc][t2][0]=v.x; hreg[mloc][t2][1]=v.y;
      hreg[mloc][t2][2]=v.z; hreg[mloc][t2][3]=v.w;
      __hip_bfloat162 c01 = __float22bfloat162_rn(make_float2(v.x,v.y));
      __hip_bfloat162 c23 = __float22bfloat162_rn(make_float2(v.z,v.w));
      uint2 pk; pk.x = *(unsigned*)&c01; pk.y = *(unsigned*)&c23;
      *(uint2*)&sh_hbf[wofs[t2][mloc]] = pk;
    }
  #pragma unroll
  for (int t2=0;t2<2;++t2)
    #pragma unroll
    for (int k0=0;k0<2;++k0)
      bfofs[t2][k0] = HBF(32*Wq+16*t2+li, 32*k0+8*g);

  // qf ring init rows 0..16 (float4 granularity)
  #pragma unroll
  for (int k2=0;k2<2;++k2){
    int f4id = tid + k2*512;
    if (f4id < 17*32){
      int r = f4id >> 5, c4 = (f4id & 31)*4;
      int qrow = qseq[b*NS + r];
      float4 v = *(const float4*)&qmat[qrow*NC + c4];
      *(float4*)&sh_qf[r][c4] = v;
    }
  }
  // pre ring init: steps 0..15
  #pragma unroll
  for (int k2=0;k2<2;++k2){
    int f4id = tid + k2*512;              // 0..1023
    int u = f4id >> 6;                    // 0..15
    int inner = f4id & 63;
    int s = inner >> 4, c4 = (inner & 15)*4;
    const float* ps = (s==0)?pre2:(s==1)?pre3:(s==2)?pre4:pre5;
    float4 v = *(const float4*)&ps[(size_t)(b*NS+u)*ND + c4];
    *(float4*)(&sh_pre[u][0][0] + inner*4) = v;
  }
  if (tid==0) sh_out[0] = 0.f;
  __syncthreads();

  // bootstrap htp: q(0).h0
  {
    float part[2][4] = {{0.f,0.f,0.f,0.f},{0.f,0.f,0.f,0.f}};
    #pragma unroll
    for (int t2=0;t2<2;++t2){
      float qv = sh_qf[0][32*Wq+16*t2+li];
      #pragma unroll
      for (int mloc=0;mloc<2;++mloc)
        #pragma unroll
        for (int r2=0;r2<4;++r2)
          part[mloc][r2] = fmaf(qv, hreg[mloc][t2][r2], part[mloc][r2]);
    }
    #pragma unroll
    for (int mloc=0;mloc<2;++mloc)
      #pragma unroll
      for (int r2=0;r2<4;++r2){ float v=part[mloc][r2]; DPP_ROWSUM(v); part[mloc][r2]=v; }
    if (li==15){
      #pragma unroll
      for (int mloc=0;mloc<2;++mloc){
        float4 pv; pv.x=part[mloc][0]; pv.y=part[mloc][1]; pv.z=part[mloc][2]; pv.w=part[mloc][3];
        *(float4*)&sh_htp[Wq][16*(mm+mloc)+4*g] = pv;
      }
    }
  }
  __syncthreads();

  // q(0) row in regs
  float qc0 = sh_qf[0][32*Wq+li];
  float qc1 = sh_qf[0][32*Wq+16+li];

  // hoisted refill bases
  const float* prebase;
  { int s = l>>4;
    const float* ps = (s==0)?pre2:(s==1)?pre3:(s==2)?pre4:pre5;
    prebase = ps + (size_t)(b*NS)*ND + (l&15)*4; }

  for (int t=0; t<127; ++t){
    const int slot = t & 31, sn = (t+1) & 31;

    // ================= Phase 1 =================
    f32x4 acc[2][2];
    #pragma unroll
    for (int mloc=0;mloc<2;++mloc)
      #pragma unroll
      for (int t2=0;t2<2;++t2)
        acc[mloc][t2] = (f32x4){0.f,0.f,0.f,0.f};
    #pragma unroll
    for (int t2=0;t2<2;++t2){
      #pragma unroll
      for (int k0=0;k0<2;++k0){
        short8 bf = *(const short8*)&sh_hbf[bfofs[t2][k0]];
        acc[0][t2] = __builtin_amdgcn_mfma_f32_16x16x32_bf16(aW[0][k0], bf, acc[0][t2], 0,0,0);
        acc[1][t2] = __builtin_amdgcn_mfma_f32_16x16x32_bf16(aW[1][k0], bf, acc[1][t2], 0,0,0);
      }
    }
    float qn0 = sh_qf[sn][32*Wq+li];
    float qn1 = sh_qf[sn][32*Wq+16+li];

    if (w==4 || w==5){
      // serial chain, fully in-wave (redundant on w4,w5)
      float htv = (sh_htp[0][l]+sh_htp[1][l])+(sh_htp[2][l]+sh_htp[3][l]);
      float pv2 = sh_pre[slot][0][l], pv3 = sh_pre[slot][1][l];
      float a0=pv2,a1=0.f,a2_=0.f,a3_=0.f;
      float c0=pv3,c1=0.f,c2_=0.f,c3_=0.f;
      #pragma unroll
      for (int j=0;j<64;j+=4){
        float h0_=rl(htv,j), h1_=rl(htv,j+1), h2_=rl(htv,j+2), h3_=rl(htv,j+3);
        a0 =fmaf(h0_,ws2[j  ],a0 ); c0 =fmaf(h0_,ws3[j  ],c0 );
        a1 =fmaf(h1_,ws2[j+1],a1 ); c1 =fmaf(h1_,ws3[j+1],c1 );
        a2_=fmaf(h2_,ws2[j+2],a2_); c2_=fmaf(h2_,ws3[j+2],c2_);
        a3_=fmaf(h3_,ws2[j+3],a3_); c3_=fmaf(h3_,ws3[j+3],c3_);
      }
      float a2p=(a0+a1)+(a2_+a3_), a3p=(c0+c1)+(c2_+c3_);
      float LGl = gsig(a3p) * gsig(a2p);            // sigma(a3)*sigma(2*a2)
      if (w==4){
        sh_LG[l] = LGl;
        float e0=sh_pre[slot][2][l],e1=0.f,e2=0.f,e3=0.f;
        #pragma unroll
        for (int j=0;j<32;j+=4){
          e0=fmaf(rl(LGl,j  ),wsB[j  ],e0); e1=fmaf(rl(LGl,j+1),wsB[j+1],e1);
          e2=fmaf(rl(LGl,j+2),wsB[j+2],e2); e3=fmaf(rl(LGl,j+3),wsB[j+3],e3);
        }
        sh_lgp[0][l] = (e0+e1)+(e2+e3);
      } else {
        float e0=0.f,e1=0.f,e2=0.f,e3=0.f;
        #pragma unroll
        for (int j=0;j<32;j+=4){
          e0=fmaf(rl(LGl,32+j  ),wsB[j  ],e0); e1=fmaf(rl(LGl,32+j+1),wsB[j+1],e1);
          e2=fmaf(rl(LGl,32+j+2),wsB[j+2],e2); e3=fmaf(rl(LGl,32+j+3),wsB[j+3],e3);
        }
        sh_lgp[1][l] = (e0+e1)+(e2+e3);
      }
    } else if (w==6){
      if (t > 0){
        float htv = (sh_htp[0][l]+sh_htp[1][l])+(sh_htp[2][l]+sh_htp[3][l]);
        float z0=sh_pre[slot][3][l],z1=0.f,z2=0.f,z3=0.f;
        #pragma unroll
        for (int j=0;j<64;j+=4){
          z0=fmaf(rl(htv,j  ),ws2[j  ],z0); z1=fmaf(rl(htv,j+1),ws2[j+1],z1);
          z2=fmaf(rl(htv,j+2),ws2[j+2],z2); z3=fmaf(rl(htv,j+3),ws2[j+3],z3);
        }
        float yv = gsig((z0+z1)+(z2+z3));
        DPP_ROWSUM(yv);
        float s = (rl(yv,15)+rl(yv,31))+(rl(yv,47)+rl(yv,63));
        if (l==0) sh_out[t] = s*(1.f/64.f);
      }
    } else if (w==3){
      if ((t&15)==0){
        int t0r = t+17;
        #pragma unroll
        for (int rep=0; rep<8; ++rep){
          int f4id = rep*64 + l;
          int r = t0r + (f4id>>5);
          int c4 = (f4id & 31)*4;
          if (r < NS){
            int qrow = qseq[b*NS + r];
            float4 v = *(const float4*)&qmat[qrow*NC + c4];
            *(float4*)&sh_qf[r&31][c4] = v;
          }
        }
      }
    } else if (w==7){
      if ((t&15)==0){
        #pragma unroll
        for (int rep=0; rep<16; ++rep){
          int u = t+16+rep;
          if (u < NS){
            float4 v = *(const float4*)&prebase[(size_t)u*ND];
            *(float4*)(&sh_pre[u&31][0][0] + l*4) = v;
          }
        }
      }
    }
    __syncthreads();

    // ================= Phase 2 =================
    {
      float4 LG4[2]; float gi[2][4];
      #pragma unroll
      for (int mloc=0;mloc<2;++mloc){
        int d0 = 16*(mm+mloc)+4*g;
        LG4[mloc] = *(const float4*)&sh_LG[d0];
        float4 g0v = *(const float4*)&sh_lgp[0][d0];
        float4 g1v = *(const float4*)&sh_lgp[1][d0];
        gi[mloc][0]=g0v.x+g1v.x; gi[mloc][1]=g0v.y+g1v.y;
        gi[mloc][2]=g0v.z+g1v.z; gi[mloc][3]=g0v.w+g1v.w;
      }
      float part[2][4] = {{0.f,0.f,0.f,0.f},{0.f,0.f,0.f,0.f}};
      #pragma unroll
      for (int t2=0;t2<2;++t2){
        float qcv = t2 ? qc1 : qc0;
        float qnv = t2 ? qn1 : qn0;
        #pragma unroll
        for (int mloc=0;mloc<2;++mloc){
          float lg4a[4] = {LG4[mloc].x, LG4[mloc].y, LG4[mloc].z, LG4[mloc].w};
          float hn[4];
          #pragma unroll
          for (int r2=0;r2<4;++r2){
            float gam = gsig(acc[mloc][t2][r2] + gi[mloc][r2]);
            hn[r2] = fmaf(qcv, lg4a[r2], gam*hreg[mloc][t2][r2]);
            hreg[mloc][t2][r2] = hn[r2];
            part[mloc][r2] = fmaf(qnv, hn[r2], part[mloc][r2]);
          }
          __hip_bfloat162 c01 = __float22bfloat162_rn(make_float2(hn[0],hn[1]));
          __hip_bfloat162 c23 = __float22bfloat162_rn(make_float2(hn[2],hn[3]));
          uint2 pk; pk.x=*(unsigned*)&c01; pk.y=*(unsigned*)&c23;
          *(uint2*)&sh_hbf[wofs[t2][mloc]] = pk;
        }
      }
      #pragma unroll
      for (int mloc=0;mloc<2;++mloc)
        #pragma unroll
        for (int r2=0;r2<4;++r2){ float v=part[mloc][r2]; DPP_ROWSUM(v); part[mloc][r2]=v; }
      if (li==15){
        #pragma unroll
        for (int mloc=0;mloc<2;++mloc){
          float4 pv; pv.x=part[mloc][0]; pv.y=part[mloc][1]; pv.z=part[mloc][2]; pv.w=part[mloc][3];
          *(float4*)&sh_htp[Wq][16*(mm+mloc)+4*g] = pv;
        }
      }
      qc0 = qn0; qc1 = qn1;
    }
    __syncthreads();
  }

  // final output position 127 (sh_htp = q(127).h(127))
  if (w==6){
    float htv = (sh_htp[0][l]+sh_htp[1][l])+(sh_htp[2][l]+sh_htp[3][l]);
    float z0=sh_pre[31][3][l],z1=0.f,z2=0.f,z3=0.f;
    #pragma unroll
    for (int j=0;j<64;j+=4){
      z0=fmaf(rl(htv,j  ),ws2[j  ],z0); z1=fmaf(rl(htv,j+1),ws2[j+1],z1);
      z2=fmaf(rl(htv,j+2),ws2[j+2],z2); z3=fmaf(rl(htv,j+3),ws2[j+3],z3);
    }
    float yv = gsig((z0+z1)+(z2+z3));
    DPP_ROWSUM(yv);
    float s = (rl(yv,15)+rl(yv,31))+(rl(yv,47)+rl(yv,63));
    if (l==0) sh_out[127] = s*(1.f/64.f);
  }
  __syncthreads();
  if (tid < NS) out[b*NS + tid] = sh_out[tid];
}

extern "C" void kernel_launch(void* const* d_in, const int* in_sizes, int n_in,
                              void* d_out, int out_size, void* d_ws, size_t ws_size,
                              hipStream_t stream)
{
  const int*   qseq  = (const int*)d_in[0];
  const int*   cseq  = (const int*)d_in[1];
  const int*   itseq = (const int*)d_in[2];
  const int*   atseq = (const int*)d_in[3];
  const float* E_q   = (const float*)d_in[4];
  const float* E_c   = (const float*)d_in[5];
  const float* E_it  = (const float*)d_in[6];
  const float* E_at  = (const float*)d_in[7];
  const float* qmat  = (const float*)d_in[8];
  const float* h0    = (const float*)d_in[9];
  const float* W1    = (const float*)d_in[10];
  const float* b1    = (const float*)d_in[11];
  const float* W2    = (const float*)d_in[12];
  const float* b2    = (const float*)d_in[13];
  const float* W3    = (const float*)d_in[14];
  const float* b3    = (const float*)d_in[15];
  const float* W4    = (const float*)d_in[16];
  const float* b4    = (const float*)d_in[17];
  const float* W5    = (const float*)d_in[18];
  const float* b5    = (const float*)d_in[19];
  float* out = (float*)d_out;

  float* wsf  = (float*)d_ws;
  float* pre2 = wsf;
  float* pre3 = wsf + 1*POS*ND;
  float* pre4 = wsf + 2*POS*ND;
  float* pre5 = wsf + 3*POS*ND;

  lpkt_pre<<<1024, 64, 0, stream>>>(qseq, cseq, itseq, atseq,
                                    E_q, E_c, E_it, E_at,
                                    W1, b1, W2, b2, W3, b3, W4, b4, W5, b5,
                                    pre2, pre3, pre4, pre5);
  lpkt_seq<<<128, 512, 0, stream>>>(qseq, qmat, h0, W2, W3, W4, W5,
                                    pre2, pre3, pre4, pre5, out);
}

// Round 7
// 289.819 us; speedup vs baseline: 1.2611x; 1.1615x over previous
//
#include <hip/hip_runtime.h>
#include <hip/hip_bf16.h>

// LPKT forward. B=128, S=128, C=128, D=64.
//  - pre1/pre2: parallel precompute (high-occupancy, 4 positions/block),
//    outputs pre-scaled by -log2e (pre2 by -2log2e) for exp2-based sigmoids.
//  - lpkt_seq: one 512-thread block per batch, 127-step recurrence, TWO
//    barriers per step. h in registers (8 waves x 32c x 32d), bf16 shadow in
//    LDS for MFMA. Serial chain redundantly in w4/w5 with REGISTER-resident
//    weights (waves_per_eu(2,2) -> 256-VGPR budget, no spill). y in w6;
//    ring refills isolated to w3 (q rows) / w7 (pre streams).

#define NB 128
#define NS 128
#define NC 128
#define ND 64
#define POS (NB*NS)

typedef __attribute__((ext_vector_type(8))) short short8;
typedef __attribute__((ext_vector_type(4))) float f32x4;

__device__ __forceinline__ float rl(float v,int j){
  return __int_as_float(__builtin_amdgcn_readlane(__float_as_int(v), j));
}
#define HBF(c, d) ((((c)<<6) + (d)) ^ (((c)&7)<<3))
#define DPP_ADD(v, CTRL) ((v) + __int_as_float(__builtin_amdgcn_update_dpp(0, __float_as_int(v), CTRL, 0xF, 0xF, true)))
#define DPP_ROWSUM(v) do { v = DPP_ADD(v,0x111); v = DPP_ADD(v,0x112); v = DPP_ADD(v,0x114); v = DPP_ADD(v,0x118); } while(0)

#define SC1 (-1.4426950408889634f)   /* -log2(e) */

__device__ __forceinline__ float gsig(float zp){   // sigmoid given pre-scaled arg
  return __builtin_amdgcn_rcpf(1.f + __builtin_amdgcn_exp2f(zp));
}

// ---------------- P1: AL = [e,at,c]@W1+b1 ; pre4 = (it@W4c+b4)*SC1 ; pre5 = (e@W5a+b5)*SC1
__global__ __launch_bounds__(64) void lpkt_pre1(
    const int* __restrict__ qseq, const int* __restrict__ cseq,
    const int* __restrict__ itseq, const int* __restrict__ atseq,
    const float* __restrict__ E_q, const float* __restrict__ E_c,
    const float* __restrict__ E_it, const float* __restrict__ E_at,
    const float* __restrict__ W1, const float* __restrict__ b1,
    const float* __restrict__ W4, const float* __restrict__ b4,
    const float* __restrict__ W5, const float* __restrict__ b5,
    float* __restrict__ AL, float* __restrict__ pre4, float* __restrict__ pre5)
{
  __shared__ float sx[4][192];
  __shared__ float sit[4][64];
  const int d = threadIdx.x;
  #pragma unroll
  for (int i = 0; i < 4; ++i) {
    int p = blockIdx.x + i*4096;
    sx[i][d]      = E_q[qseq[p]*ND + d];
    sx[i][64+d]   = E_at[atseq[p]*ND + d];
    sx[i][128+d]  = E_c[cseq[p]*ND + d];
    sit[i][d]     = E_it[itseq[p]*ND + d];
  }
  __syncthreads();
  float al[4], p4[4], p5[4];
  const float b1d = b1[d], b4d = b4[d], b5d = b5[d];
  #pragma unroll
  for (int i = 0; i < 4; ++i) { al[i] = b1d; p4[i] = b4d; p5[i] = b5d; }
  for (int k = 0; k < 192; ++k) {
    float wv = W1[k*ND + d];
    #pragma unroll
    for (int i = 0; i < 4; ++i) al[i] = fmaf(sx[i][k], wv, al[i]);
  }
  for (int k = 0; k < 64; ++k) {
    float wv4 = W4[(128+k)*ND + d];
    float wv5 = W5[k*ND + d];
    #pragma unroll
    for (int i = 0; i < 4; ++i) {
      p4[i] = fmaf(sit[i][k], wv4, p4[i]);
      p5[i] = fmaf(sx[i][k],  wv5, p5[i]);
    }
  }
  #pragma unroll
  for (int i = 0; i < 4; ++i) {
    int p = blockIdx.x + i*4096;
    AL[p*ND + d]   = al[i];
    pre4[p*ND + d] = p4[i]*SC1;
    pre5[p*ND + d] = p5[i]*SC1;
  }
}

// ---------------- P2: pre2/pre3 = ([AL(t-1)|0, it, AL(t)] @ W{2,3}[0:192] + b) * scale
__global__ __launch_bounds__(64) void lpkt_pre2(
    const int* __restrict__ itseq, const float* __restrict__ E_it,
    const float* __restrict__ AL,
    const float* __restrict__ W2, const float* __restrict__ b2,
    const float* __restrict__ W3, const float* __restrict__ b3,
    float* __restrict__ pre2, float* __restrict__ pre3)
{
  __shared__ float sx[4][192];
  const int d = threadIdx.x;
  int bs4[4];
  #pragma unroll
  for (int i = 0; i < 4; ++i) {
    int p = blockIdx.x + i*4064;
    int b = p / 127;
    int t = p - b*127;
    int bs = b*NS + t;
    bs4[i] = bs;
    sx[i][d]     = (t > 0) ? AL[(bs-1)*ND + d] : 0.f;
    sx[i][64+d]  = E_it[itseq[bs]*ND + d];
    sx[i][128+d] = AL[bs*ND + d];
  }
  __syncthreads();
  float a2[4], a3[4];
  const float b2d = b2[d], b3d = b3[d];
  #pragma unroll
  for (int i = 0; i < 4; ++i) { a2[i] = b2d; a3[i] = b3d; }
  for (int k = 0; k < 192; ++k) {
    float w2v = W2[k*ND + d];
    float w3v = W3[k*ND + d];
    #pragma unroll
    for (int i = 0; i < 4; ++i) {
      a2[i] = fmaf(sx[i][k], w2v, a2[i]);
      a3[i] = fmaf(sx[i][k], w3v, a3[i]);
    }
  }
  #pragma unroll
  for (int i = 0; i < 4; ++i) {
    pre2[bs4[i]*ND + d] = a2[i]*(2.f*SC1);
    pre3[bs4[i]*ND + d] = a3[i]*SC1;
  }
}

// ---------------- sequential recurrence
__global__ __attribute__((amdgpu_flat_work_group_size(512,512), amdgpu_waves_per_eu(2,2)))
void lpkt_seq(
    const int* __restrict__ qseq, const float* __restrict__ qmat,
    const float* __restrict__ h0,
    const float* __restrict__ W2, const float* __restrict__ W3,
    const float* __restrict__ W4, const float* __restrict__ W5,
    const float* __restrict__ pre2, const float* __restrict__ pre3,
    const float* __restrict__ pre4, const float* __restrict__ pre5,
    float* __restrict__ out)
{
  __shared__ __align__(16) unsigned short sh_hbf[NC*ND];  // 16KB bf16 shadow
  __shared__ float sh_pre[32][4][64];                     // 32KB stream ring [slot][stream][d]
  __shared__ float sh_qf[32][NC];                         // 16KB q-row ring
  __shared__ float sh_htp[4][64];
  __shared__ float sh_LG[64];
  __shared__ float sh_lgp[2][64];
  __shared__ float sh_out[NS];

  const int tid = threadIdx.x;
  const int w = tid>>6, l = tid&63;
  const int g = l>>4, li = l&15;
  const int b = blockIdx.x;
  const int Wq = w & 3, mm = (w>>2)*2;

  if (w==4 || w==5) __builtin_amdgcn_s_setprio(1);

  // MFMA A-frags: W4a columns scaled by -log2e
  short8 aW[2][2];
  #pragma unroll
  for (int mloc=0;mloc<2;++mloc)
    #pragma unroll
    for (int k0=0;k0<2;++k0){
      short8 v;
      #pragma unroll
      for (int j=0;j<8;++j){
        __hip_bfloat16 hb = __float2bfloat16(W4[(32*k0+8*g+j)*ND + 16*(mm+mloc)+li] * SC1);
        v[j] = *(short*)&hb;
      }
      aW[mloc][k0] = v;
    }

  // chain weights (register-resident)
  float ws2[64], ws3[64], wsB[32];
  if (w==4 || w==5){
    #pragma unroll
    for (int j=0;j<64;++j) ws2[j] = W2[(192+j)*ND + l] * (2.f*SC1);
    #pragma unroll
    for (int j=0;j<64;++j) ws3[j] = W3[(192+j)*ND + l] * SC1;
    const float* pb = W4 + ((w==4)?64:96)*ND;
    #pragma unroll
    for (int j=0;j<32;++j) wsB[j] = pb[j*ND + l] * SC1;
  } else if (w==6){
    #pragma unroll
    for (int j=0;j<64;++j) ws2[j] = W5[(64+j)*ND + l] * SC1;
  }

  // h init in regs + bf16 shadow
  float hreg[2][2][4];
  int wofs[2][2], bfofs[2][2];
  #pragma unroll
  for (int mloc=0;mloc<2;++mloc)
    #pragma unroll
    for (int t2=0;t2<2;++t2){
      int c  = 32*Wq + 16*t2 + li;
      int d0 = 16*(mm+mloc) + 4*g;
      wofs[t2][mloc] = HBF(c, d0);
      float4 v = *(const float4*)&h0[c*ND + d0];
      hreg[mloc][t2][0]=v.x; hreg[mloc][t2][1]=v.y;
      hreg[mloc][t2][2]=v.z; hreg[mloc][t2][3]=v.w;
      __hip_bfloat162 c01 = __float22bfloat162_rn(make_float2(v.x,v.y));
      __hip_bfloat162 c23 = __float22bfloat162_rn(make_float2(v.z,v.w));
      uint2 pk; pk.x = *(unsigned*)&c01; pk.y = *(unsigned*)&c23;
      *(uint2*)&sh_hbf[wofs[t2][mloc]] = pk;
    }
  #pragma unroll
  for (int t2=0;t2<2;++t2)
    #pragma unroll
    for (int k0=0;k0<2;++k0)
      bfofs[t2][k0] = HBF(32*Wq+16*t2+li, 32*k0+8*g);

  // qf ring init rows 0..16 (float4 granularity)
  #pragma unroll
  for (int k2=0;k2<2;++k2){
    int f4id = tid + k2*512;
    if (f4id < 17*32){
      int r = f4id >> 5, c4 = (f4id & 31)*4;
      int qrow = qseq[b*NS + r];
      float4 v = *(const float4*)&qmat[qrow*NC + c4];
      *(float4*)&sh_qf[r][c4] = v;
    }
  }
  // pre ring init: steps 0..15
  #pragma unroll
  for (int k2=0;k2<2;++k2){
    int f4id = tid + k2*512;              // 0..1023
    int u = f4id >> 6;                    // 0..15
    int inner = f4id & 63;
    int s = inner >> 4, c4 = (inner & 15)*4;
    const float* ps = (s==0)?pre2:(s==1)?pre3:(s==2)?pre4:pre5;
    float4 v = *(const float4*)&ps[(size_t)(b*NS+u)*ND + c4];
    *(float4*)(&sh_pre[u][0][0] + inner*4) = v;
  }
  if (tid==0) sh_out[0] = 0.f;
  __syncthreads();

  // bootstrap htp: q(0).h0
  {
    float part[2][4] = {{0.f,0.f,0.f,0.f},{0.f,0.f,0.f,0.f}};
    #pragma unroll
    for (int t2=0;t2<2;++t2){
      float qv = sh_qf[0][32*Wq+16*t2+li];
      #pragma unroll
      for (int mloc=0;mloc<2;++mloc)
        #pragma unroll
        for (int r2=0;r2<4;++r2)
          part[mloc][r2] = fmaf(qv, hreg[mloc][t2][r2], part[mloc][r2]);
    }
    #pragma unroll
    for (int mloc=0;mloc<2;++mloc)
      #pragma unroll
      for (int r2=0;r2<4;++r2){ float v=part[mloc][r2]; DPP_ROWSUM(v); part[mloc][r2]=v; }
    if (li==15){
      #pragma unroll
      for (int mloc=0;mloc<2;++mloc){
        float4 pv; pv.x=part[mloc][0]; pv.y=part[mloc][1]; pv.z=part[mloc][2]; pv.w=part[mloc][3];
        *(float4*)&sh_htp[Wq][16*(mm+mloc)+4*g] = pv;
      }
    }
  }
  __syncthreads();

  // q(0) row in regs
  float qc0 = sh_qf[0][32*Wq+li];
  float qc1 = sh_qf[0][32*Wq+16+li];

  // hoisted refill bases
  const float* prebase;
  { int s = l>>4;
    const float* ps = (s==0)?pre2:(s==1)?pre3:(s==2)?pre4:pre5;
    prebase = ps + (size_t)(b*NS)*ND + (l&15)*4; }

  for (int t=0; t<127; ++t){
    const int slot = t & 31, sn = (t+1) & 31;

    // ================= Phase 1 =================
    f32x4 acc[2][2];
    #pragma unroll
    for (int mloc=0;mloc<2;++mloc)
      #pragma unroll
      for (int t2=0;t2<2;++t2)
        acc[mloc][t2] = (f32x4){0.f,0.f,0.f,0.f};
    #pragma unroll
    for (int t2=0;t2<2;++t2){
      #pragma unroll
      for (int k0=0;k0<2;++k0){
        short8 bf = *(const short8*)&sh_hbf[bfofs[t2][k0]];
        acc[0][t2] = __builtin_amdgcn_mfma_f32_16x16x32_bf16(aW[0][k0], bf, acc[0][t2], 0,0,0);
        acc[1][t2] = __builtin_amdgcn_mfma_f32_16x16x32_bf16(aW[1][k0], bf, acc[1][t2], 0,0,0);
      }
    }
    float qn0 = sh_qf[sn][32*Wq+li];
    float qn1 = sh_qf[sn][32*Wq+16+li];

    if (w==4 || w==5){
      // serial chain, fully in-wave (redundant on w4,w5)
      float htv = (sh_htp[0][l]+sh_htp[1][l])+(sh_htp[2][l]+sh_htp[3][l]);
      float pv2 = sh_pre[slot][0][l], pv3 = sh_pre[slot][1][l];
      float a0=pv2,a1=0.f,a2_=0.f,a3_=0.f;
      float c0=pv3,c1=0.f,c2_=0.f,c3_=0.f;
      #pragma unroll
      for (int j=0;j<64;j+=4){
        float h0_=rl(htv,j), h1_=rl(htv,j+1), h2_=rl(htv,j+2), h3_=rl(htv,j+3);
        a0 =fmaf(h0_,ws2[j  ],a0 ); c0 =fmaf(h0_,ws3[j  ],c0 );
        a1 =fmaf(h1_,ws2[j+1],a1 ); c1 =fmaf(h1_,ws3[j+1],c1 );
        a2_=fmaf(h2_,ws2[j+2],a2_); c2_=fmaf(h2_,ws3[j+2],c2_);
        a3_=fmaf(h3_,ws2[j+3],a3_); c3_=fmaf(h3_,ws3[j+3],c3_);
      }
      float a2p=(a0+a1)+(a2_+a3_), a3p=(c0+c1)+(c2_+c3_);
      float LGl = gsig(a3p) * gsig(a2p);            // sigma(a3)*sigma(2*a2)
      if (w==4){
        sh_LG[l] = LGl;
        float e0=sh_pre[slot][2][l],e1=0.f,e2=0.f,e3=0.f;
        #pragma unroll
        for (int j=0;j<32;j+=4){
          e0=fmaf(rl(LGl,j  ),wsB[j  ],e0); e1=fmaf(rl(LGl,j+1),wsB[j+1],e1);
          e2=fmaf(rl(LGl,j+2),wsB[j+2],e2); e3=fmaf(rl(LGl,j+3),wsB[j+3],e3);
        }
        sh_lgp[0][l] = (e0+e1)+(e2+e3);
      } else {
        float e0=0.f,e1=0.f,e2=0.f,e3=0.f;
        #pragma unroll
        for (int j=0;j<32;j+=4){
          e0=fmaf(rl(LGl,32+j  ),wsB[j  ],e0); e1=fmaf(rl(LGl,32+j+1),wsB[j+1],e1);
          e2=fmaf(rl(LGl,32+j+2),wsB[j+2],e2); e3=fmaf(rl(LGl,32+j+3),wsB[j+3],e3);
        }
        sh_lgp[1][l] = (e0+e1)+(e2+e3);
      }
    } else if (w==6){
      if (t > 0){
        float htv = (sh_htp[0][l]+sh_htp[1][l])+(sh_htp[2][l]+sh_htp[3][l]);
        float z0=sh_pre[slot][3][l],z1=0.f,z2=0.f,z3=0.f;
        #pragma unroll
        for (int j=0;j<64;j+=4){
          z0=fmaf(rl(htv,j  ),ws2[j  ],z0); z1=fmaf(rl(htv,j+1),ws2[j+1],z1);
          z2=fmaf(rl(htv,j+2),ws2[j+2],z2); z3=fmaf(rl(htv,j+3),ws2[j+3],z3);
        }
        float yv = gsig((z0+z1)+(z2+z3));
        DPP_ROWSUM(yv);
        float s = (rl(yv,15)+rl(yv,31))+(rl(yv,47)+rl(yv,63));
        if (l==0) sh_out[t] = s*(1.f/64.f);
      }
    } else if (w==3){
      if ((t&15)==0){
        int t0r = t+17;
        #pragma unroll
        for (int rep=0; rep<8; ++rep){
          int f4id = rep*64 + l;
          int r = t0r + (f4id>>5);
          int c4 = (f4id & 31)*4;
          if (r < NS){
            int qrow = qseq[b*NS + r];
            float4 v = *(const float4*)&qmat[qrow*NC + c4];
            *(float4*)&sh_qf[r&31][c4] = v;
          }
        }
      }
    } else if (w==7){
      if ((t&15)==0){
        #pragma unroll
        for (int rep=0; rep<16; ++rep){
          int u = t+16+rep;
          if (u < NS){
            float4 v = *(const float4*)&prebase[(size_t)u*ND];
            *(float4*)(&sh_pre[u&31][0][0] + l*4) = v;
          }
        }
      }
    }
    __syncthreads();

    // ================= Phase 2 =================
    {
      float4 LG4[2]; float gi[2][4];
      #pragma unroll
      for (int mloc=0;mloc<2;++mloc){
        int d0 = 16*(mm+mloc)+4*g;
        LG4[mloc] = *(const float4*)&sh_LG[d0];
        float4 g0v = *(const float4*)&sh_lgp[0][d0];
        float4 g1v = *(const float4*)&sh_lgp[1][d0];
        gi[mloc][0]=g0v.x+g1v.x; gi[mloc][1]=g0v.y+g1v.y;
        gi[mloc][2]=g0v.z+g1v.z; gi[mloc][3]=g0v.w+g1v.w;
      }
      float part[2][4] = {{0.f,0.f,0.f,0.f},{0.f,0.f,0.f,0.f}};
      #pragma unroll
      for (int t2=0;t2<2;++t2){
        float qcv = t2 ? qc1 : qc0;
        float qnv = t2 ? qn1 : qn0;
        #pragma unroll
        for (int mloc=0;mloc<2;++mloc){
          float lg4a[4] = {LG4[mloc].x, LG4[mloc].y, LG4[mloc].z, LG4[mloc].w};
          float hn[4];
          #pragma unroll
          for (int r2=0;r2<4;++r2){
            float gam = gsig(acc[mloc][t2][r2] + gi[mloc][r2]);
            hn[r2] = fmaf(qcv, lg4a[r2], gam*hreg[mloc][t2][r2]);
            hreg[mloc][t2][r2] = hn[r2];
            part[mloc][r2] = fmaf(qnv, hn[r2], part[mloc][r2]);
          }
          __hip_bfloat162 c01 = __float22bfloat162_rn(make_float2(hn[0],hn[1]));
          __hip_bfloat162 c23 = __float22bfloat162_rn(make_float2(hn[2],hn[3]));
          uint2 pk; pk.x=*(unsigned*)&c01; pk.y=*(unsigned*)&c23;
          *(uint2*)&sh_hbf[wofs[t2][mloc]] = pk;
        }
      }
      #pragma unroll
      for (int mloc=0;mloc<2;++mloc)
        #pragma unroll
        for (int r2=0;r2<4;++r2){ float v=part[mloc][r2]; DPP_ROWSUM(v); part[mloc][r2]=v; }
      if (li==15){
        #pragma unroll
        for (int mloc=0;mloc<2;++mloc){
          float4 pv; pv.x=part[mloc][0]; pv.y=part[mloc][1]; pv.z=part[mloc][2]; pv.w=part[mloc][3];
          *(float4*)&sh_htp[Wq][16*(mm+mloc)+4*g] = pv;
        }
      }
      qc0 = qn0; qc1 = qn1;
    }
    __syncthreads();
  }

  // final output position 127 (sh_htp = q(127).h(127))
  if (w==6){
    float htv = (sh_htp[0][l]+sh_htp[1][l])+(sh_htp[2][l]+sh_htp[3][l]);
    float z0=sh_pre[31][3][l],z1=0.f,z2=0.f,z3=0.f;
    #pragma unroll
    for (int j=0;j<64;j+=4){
      z0=fmaf(rl(htv,j  ),ws2[j  ],z0); z1=fmaf(rl(htv,j+1),ws2[j+1],z1);
      z2=fmaf(rl(htv,j+2),ws2[j+2],z2); z3=fmaf(rl(htv,j+3),ws2[j+3],z3);
    }
    float yv = gsig((z0+z1)+(z2+z3));
    DPP_ROWSUM(yv);
    float s = (rl(yv,15)+rl(yv,31))+(rl(yv,47)+rl(yv,63));
    if (l==0) sh_out[127] = s*(1.f/64.f);
  }
  __syncthreads();
  if (tid < NS) out[b*NS + tid] = sh_out[tid];
}

extern "C" void kernel_launch(void* const* d_in, const int* in_sizes, int n_in,
                              void* d_out, int out_size, void* d_ws, size_t ws_size,
                              hipStream_t stream)
{
  const int*   qseq  = (const int*)d_in[0];
  const int*   cseq  = (const int*)d_in[1];
  const int*   itseq = (const int*)d_in[2];
  const int*   atseq = (const int*)d_in[3];
  const float* E_q   = (const float*)d_in[4];
  const float* E_c   = (const float*)d_in[5];
  const float* E_it  = (const float*)d_in[6];
  const float* E_at  = (const float*)d_in[7];
  const float* qmat  = (const float*)d_in[8];
  const float* h0    = (const float*)d_in[9];
  const float* W1    = (const float*)d_in[10];
  const float* b1    = (const float*)d_in[11];
  const float* W2    = (const float*)d_in[12];
  const float* b2    = (const float*)d_in[13];
  const float* W3    = (const float*)d_in[14];
  const float* b3    = (const float*)d_in[15];
  const float* W4    = (const float*)d_in[16];
  const float* b4    = (const float*)d_in[17];
  const float* W5    = (const float*)d_in[18];
  const float* b5    = (const float*)d_in[19];
  float* out = (float*)d_out;

  float* wsf  = (float*)d_ws;
  float* AL   = wsf;
  float* pre2 = wsf + 1*POS*ND;
  float* pre3 = wsf + 2*POS*ND;
  float* pre4 = wsf + 3*POS*ND;
  float* pre5 = wsf + 4*POS*ND;

  lpkt_pre1<<<4096, 64, 0, stream>>>(qseq, cseq, itseq, atseq,
                                     E_q, E_c, E_it, E_at,
                                     W1, b1, W4, b4, W5, b5,
                                     AL, pre4, pre5);
  lpkt_pre2<<<4064, 64, 0, stream>>>(itseq, E_it, AL, W2, b2, W3, b3, pre2, pre3);
  lpkt_seq<<<128, 512, 0, stream>>>(qseq, qmat, h0, W2, W3, W4, W5,
                                    pre2, pre3, pre4, pre5, out);
}